// Round 18
// baseline (62.634 us; speedup 1.0000x reference)
//
#include <hip/hip_runtime.h>
#include <hip/hip_fp16.h>

// GCN layer: out = relu( (D^-1/2 A D^-1/2 x) @ W + b )
// N=50000 nodes, E=800000 edges, C=64 channels, fp32 in/out.
//
// R18 = R17 backbone with the per-bucket SORT fused into the gather kernel:
// srcs never round-trips global memory (was 3.2MB write + 2.4MB read + a
// launch). build shrinks to build_lite (histogram -> xsh).
//   clearcur:    bcur[] = 0 (tiny kernel; never hipMemset tiny buffers — R13)
//   bin:         per-block LDS histogram + per-edge rank, 1 reservation atomic
//                per (block,bucket); packed (col_lo<<16|src) u32 at bkt*cap+rel
//   build_lite:  per-bucket histogram -> xsh = half(deg^-1/2 * x); block 0
//                writes zero row xsh[N]  (verified correct in R16's run)
//   gather_fused: block = bucket. Sort phase (R17-build's exact code):
//                histogram -> 8-padded scan -> LDS scatter into sl[] (pad
//                slots = N -> zero row). Gather phase (R17-proven): 16-lane
//                group per node, per 8 edges one ds_read_b128 of srcs + 8
//                xsh row loads in flight; dis recomputed as rsqrtf(deg);
//                4 rounds x 32 nodes of the R8-proven linear epilogue.
// No float atomics anywhere (R16 measured LDS ds_add_f32 at ~15x cost).

#define C_CH 64
#define BW   128        // bucket width in nodes
#define BSH  7          // log2(BW)
#define MAXBUK 512      // >= ceil(N/BW) = 391
#define BIN_CHUNK 2048  // edges per bin block (391 blocks)

// ---- clear bucket cursors ---------------------------------------------------
__global__ void clearcur_kernel(int* __restrict__ bcur, int nbuk) {
    int i = blockIdx.x * blockDim.x + threadIdx.x;
    if (i < nbuk) bcur[i] = 0;
}

// ---- bin: scatter edges into fixed-capacity bucket regions (R14-proven) -----
__global__ void __launch_bounds__(256)
bin_kernel(const int* __restrict__ row, const int* __restrict__ col,
           int* __restrict__ bcur, unsigned* __restrict__ epk,
           int E, int nbuk, int cap) {
    __shared__ int h[MAXBUK];                 // block-local bucket counts
    __shared__ int rb[MAXBUK];                // block's reserved rel-base per bucket
    __shared__ unsigned short rank[BIN_CHUNK];// per-edge local rank
    int tid = threadIdx.x;
    int e0 = blockIdx.x * BIN_CHUNK;
    int cntE = E - e0; if (cntE > BIN_CHUNK) cntE = BIN_CHUNK;

    for (int i = tid; i < nbuk; i += 256) h[i] = 0;
    __syncthreads();

    const int4* col4 = (const int4*)(col + e0);   // e0 is 2048-aligned
    const int4* row4 = (const int4*)(row + e0);
    int cnt4 = cntE >> 2;
    for (int i = tid; i < cnt4; i += 256) {       // pass 1: ranks (int4 loads)
        int4 c = col4[i];
        rank[4*i+0] = (unsigned short)atomicAdd(&h[c.x >> BSH], 1);
        rank[4*i+1] = (unsigned short)atomicAdd(&h[c.y >> BSH], 1);
        rank[4*i+2] = (unsigned short)atomicAdd(&h[c.z >> BSH], 1);
        rank[4*i+3] = (unsigned short)atomicAdd(&h[c.w >> BSH], 1);
    }
    for (int i = (cnt4 << 2) + tid; i < cntE; i += 256)
        rank[i] = (unsigned short)atomicAdd(&h[col[e0 + i] >> BSH], 1);
    __syncthreads();

    for (int i = tid; i < nbuk; i += 256)         // 1 atomic/(block,bucket)
        rb[i] = h[i] ? atomicAdd(&bcur[i], h[i]) : 0;   // bcur starts at 0
    __syncthreads();

    for (int i = tid; i < cnt4; i += 256) {       // pass 2: write packed edges
        int4 c = col4[i];
        int4 r = row4[i];
        #pragma unroll
        for (int j = 0; j < 4; ++j) {
            int cc = (j == 0) ? c.x : (j == 1) ? c.y : (j == 2) ? c.z : c.w;
            int rr = (j == 0) ? r.x : (j == 1) ? r.y : (j == 2) ? r.z : r.w;
            int bkt = cc >> BSH;
            int rel = rb[bkt] + (int)rank[4*i+j];
            if (rel < cap)                        // safety clamp (never hit here)
                epk[bkt * cap + rel] = ((unsigned)(cc & (BW - 1)) << 16) | (unsigned)rr;
        }
    }
    for (int i = (cnt4 << 2) + tid; i < cntE; i += 256) {
        int cc = col[e0 + i];
        int bkt = cc >> BSH;
        int rel = rb[bkt] + (int)rank[i];
        if (rel < cap)
            epk[bkt * cap + rel] = ((unsigned)(cc & (BW - 1)) << 16) | (unsigned)row[e0 + i];
    }
}

// ---- build_lite: histogram -> xsh (no sort; R16-verified) -------------------
__global__ void __launch_bounds__(256)
build_lite_kernel(const unsigned* __restrict__ epk, const int* __restrict__ bcur,
                  const float* __restrict__ x, __half* __restrict__ xsh,
                  int N, int cap) {
    __shared__ int cnt[BW];
    __shared__ float dv[BW];
    int tid = threadIdx.x;
    int b   = blockIdx.x;
    int base = b * cap;
    int cb = bcur[b]; if (cb > cap) cb = cap;
    int nb0 = b << BSH;
    int nn  = N - nb0; if (nn > BW) nn = BW;

    if (tid < BW) cnt[tid] = 0;
    __syncthreads();
    for (int i = tid; i < cb; i += 256)
        atomicAdd(&cnt[(epk[base + i] >> 16) & (BW - 1)], 1);
    __syncthreads();
    if (tid < nn) {
        int d = cnt[tid];
        dv[tid] = (d > 0) ? rsqrtf((float)d) : 0.0f;
    }
    __syncthreads();

    // xsh[n][c] = half(dis[n] * x[n][c]) for this bucket's nodes
    int tot2 = nn * (C_CH / 2);
    const float2* x2 = (const float2*)x;
    __half2* o2 = (__half2*)xsh;
    for (int i = tid; i < tot2; i += 256) {
        int nl = i >> 5;
        int c2 = i & 31;
        long long gi = (long long)(nb0 + nl) * (C_CH / 2) + c2;
        float2 v = x2[gi];
        float dn = dv[nl];
        o2[gi] = __floats2half2_rn(v.x * dn, v.y * dn);
    }
    // zero row at index N (gather's sentinel target)
    if (b == 0 && tid < C_CH / 2)
        o2[(long long)N * (C_CH / 2) + tid] = __floats2half2_rn(0.0f, 0.0f);
}

// ---- gather_fused: sort-in-LDS + gather + linear + ReLU ----------------------
// Block = bucket (128 nodes, 512 threads). Phase 1 (R17-build's proven sort):
// histogram -> 8-padded scan -> scatter srcs into sl[] (prefilled with N so
// pad slots hit the zero row). Phase 2 (R17-proven gather): 16-lane group per
// node; per 8 edges one 16B LDS read of srcs + 8 independent xsh row loads;
// 4 rounds x 32 nodes; R8-proven per-node linear epilogue per round.
__global__ void __launch_bounds__(512)
gather_fused_kernel(const uint2* __restrict__ xsh8,   // [(N+1)][16] x 8B
                    const unsigned* __restrict__ epk,
                    const int* __restrict__ bcur,
                    const float* __restrict__ W, const float* __restrict__ bvec,
                    float* __restrict__ out, int N, int cap) {
    __shared__ float Ws[C_CH * C_CH];            // 16 KB
    __shared__ float bs[C_CH];
    __shared__ unsigned short sl[4096];          // 8 KB sorted srcs
    __shared__ int cnt[BW];
    __shared__ int sc[BW];
    __shared__ int cur[BW];
    __shared__ int sstart[BW];
    __shared__ float ags[32][68];                // 8.7 KB; total ~35.6 KB -> 4 blk/CU

    int tid = threadIdx.x;
    {   // stage W as float4
        const float4* W4 = (const float4*)W;
        float4* Ws4 = (float4*)Ws;
        for (int i = tid; i < C_CH * C_CH / 4; i += 512) Ws4[i] = W4[i];
        if (tid < C_CH) bs[tid] = bvec[tid];
    }
    if (tid < BW) cnt[tid] = 0;
    for (int i = tid; i < cap && i < 4096; i += 512)  // prefill: pad -> zero row
        sl[i] = (unsigned short)N;
    __syncthreads();

    int b = blockIdx.x;
    int base = b * cap;
    int cb = bcur[b]; if (cb > cap) cb = cap;
    int nb0 = b << BSH;
    int nn  = N - nb0; if (nn > BW) nn = BW;

    // ---- sort phase (R17 build's exact structure) ----
    for (int i = tid; i < cb; i += 512)
        atomicAdd(&cnt[epk[base + i] >> 16], 1);
    __syncthreads();
    if (tid < BW) sc[tid] = (cnt[tid] + 7) & ~7;  // 8-padded degree
    __syncthreads();
    for (int off = 1; off < BW; off <<= 1) {      // inclusive scan
        int t = (tid < BW && tid >= off) ? sc[tid - off] : 0;
        __syncthreads();
        if (tid < BW) sc[tid] += t;
        __syncthreads();
    }
    if (tid < BW) {
        int d  = cnt[tid];
        int dp = (d + 7) & ~7;
        int ex = sc[tid] - dp;                    // 8-aligned exclusive offset
        cur[tid] = ex;
        sstart[tid] = ex;
    }
    __syncthreads();
    for (int i = tid; i < cb; i += 512) {         // scatter inside LDS
        unsigned p = epk[base + i];
        int pos = atomicAdd(&cur[p >> 16], 1);
        if (pos < cap && pos < 4096) sl[pos] = (unsigned short)(p & 0xFFFFu);
    }
    __syncthreads();

    // ---- gather + linear, 4 rounds x 32 nodes ----
    int g  = tid >> 4;        // group = node-in-round 0..31
    int c4 = tid & 15;        // channel quad
    #pragma unroll 1
    for (int rrd = 0; rrd < 4; ++rrd) {
        int v = rrd * 32 + g;
        bool act = (v < nn);
        if (act) {
            float4 acc = make_float4(0.f, 0.f, 0.f, 0.f);
            int s0 = sstart[v];                  // multiple of 8
            int d  = cnt[v];
            int degp = (d + 7) & ~7;
            for (int eb = 0; eb < degp; eb += 8) {
                uint4 sv = *(const uint4*)(sl + s0 + eb);  // 8 srcs, 1 LDS b128
                int r0 = (int)(sv.x & 0xFFFFu), r1 = (int)(sv.x >> 16);
                int r2 = (int)(sv.y & 0xFFFFu), r3 = (int)(sv.y >> 16);
                int r4 = (int)(sv.z & 0xFFFFu), r5 = (int)(sv.z >> 16);
                int r6 = (int)(sv.w & 0xFFFFu), r7 = (int)(sv.w >> 16);
                uint2 u0 = xsh8[r0 * 16 + c4];   // 8 independent loads in flight
                uint2 u1 = xsh8[r1 * 16 + c4];
                uint2 u2 = xsh8[r2 * 16 + c4];
                uint2 u3 = xsh8[r3 * 16 + c4];
                uint2 u4 = xsh8[r4 * 16 + c4];
                uint2 u5 = xsh8[r5 * 16 + c4];
                uint2 u6 = xsh8[r6 * 16 + c4];
                uint2 u7 = xsh8[r7 * 16 + c4];
                #pragma unroll
                for (int k = 0; k < 8; ++k) {
                    uint2 u = (k==0)?u0:(k==1)?u1:(k==2)?u2:(k==3)?u3:
                              (k==4)?u4:(k==5)?u5:(k==6)?u6:u7;
                    float2 f0 = __half22float2(*(__half2*)&u.x);
                    float2 f1 = __half22float2(*(__half2*)&u.y);
                    acc.x += f0.x; acc.y += f0.y; acc.z += f1.x; acc.w += f1.y;
                }
            }
            float dt = (d > 0) ? rsqrtf((float)d) : 0.0f;
            acc.x *= dt; acc.y *= dt; acc.z *= dt; acc.w *= dt;
            *(float4*)&ags[g][4 * c4] = acc;
        }
        __syncthreads();
        if (act) {                                // R8-proven linear epilogue
            float4 o = *(const float4*)&bs[4 * c4];
            #pragma unroll
            for (int kq = 0; kq < C_CH / 4; ++kq) {
                float4 a4 = *(const float4*)&ags[g][4 * kq];
                float4 w0 = *(const float4*)&Ws[(4 * kq + 0) * C_CH + 4 * c4];
                float4 w1 = *(const float4*)&Ws[(4 * kq + 1) * C_CH + 4 * c4];
                float4 w2 = *(const float4*)&Ws[(4 * kq + 2) * C_CH + 4 * c4];
                float4 w3 = *(const float4*)&Ws[(4 * kq + 3) * C_CH + 4 * c4];
                o.x = fmaf(a4.x, w0.x, o.x); o.y = fmaf(a4.x, w0.y, o.y);
                o.z = fmaf(a4.x, w0.z, o.z); o.w = fmaf(a4.x, w0.w, o.w);
                o.x = fmaf(a4.y, w1.x, o.x); o.y = fmaf(a4.y, w1.y, o.y);
                o.z = fmaf(a4.y, w1.z, o.z); o.w = fmaf(a4.y, w1.w, o.w);
                o.x = fmaf(a4.z, w2.x, o.x); o.y = fmaf(a4.z, w2.y, o.y);
                o.z = fmaf(a4.z, w2.z, o.z); o.w = fmaf(a4.z, w2.w, o.w);
                o.x = fmaf(a4.w, w3.x, o.x); o.y = fmaf(a4.w, w3.y, o.y);
                o.z = fmaf(a4.w, w3.z, o.z); o.w = fmaf(a4.w, w3.w, o.w);
            }
            o.x = fmaxf(o.x, 0.f); o.y = fmaxf(o.y, 0.f);
            o.z = fmaxf(o.z, 0.f); o.w = fmaxf(o.w, 0.f);
            *(float4*)&out[(long long)(nb0 + v) * C_CH + 4 * c4] = o;
        }
        __syncthreads();                          // ags reused next round
    }
}

extern "C" void kernel_launch(void* const* d_in, const int* in_sizes, int n_in,
                              void* d_out, int out_size, void* d_ws, size_t ws_size,
                              hipStream_t stream) {
    const float* x  = (const float*)d_in[0];
    const int*   ei = (const int*)  d_in[1];
    const float* W  = (const float*)d_in[2];
    const float* b  = (const float*)d_in[3];
    float* out = (float*)d_out;

    const int N = in_sizes[0] / C_CH;
    const int E = in_sizes[1] / 2;
    const int* row = ei;        // edge_index[0]
    const int* col = ei + E;    // edge_index[1]
    const int nbuk = (N + BW - 1) >> BSH;   // 391 (<= MAXBUK)

    // Bucket capacity: mean bucket = E*BW/N ~ 2048 (sd ~45); padded segments
    // total <= cb + 128*7 ~ 2950 << 4096.
    auto need = [&](int cap) {
        return (size_t)nbuk * cap * 4          // epk
             + (((size_t)nbuk * 4 + 127) & ~(size_t)127)  // bcur (padded)
             + (size_t)(N + 1) * C_CH * 2;     // xsh incl. zero row
    };
    int cap = 4096;
    if (ws_size < need(4096)) cap = 3072;

    char* ws = (char*)d_ws;
    unsigned* epk = (unsigned*)ws;      ws += (size_t)nbuk * cap * 4;
    int* bcur = (int*)ws;               ws += ((size_t)nbuk * 4 + 127) & ~(size_t)127;
    __half* xsh = (__half*)ws;          // 8B-aligned for uint2 loads

    clearcur_kernel   <<<(nbuk + 255) / 256, 256, 0, stream>>>(bcur, nbuk);
    bin_kernel        <<<(E + BIN_CHUNK - 1) / BIN_CHUNK, 256, 0, stream>>>(row, col, bcur, epk, E, nbuk, cap);
    build_lite_kernel <<<nbuk, 256, 0, stream>>>(epk, bcur, x, xsh, N, cap);
    gather_fused_kernel<<<nbuk, 512, 0, stream>>>((const uint2*)xsh, epk, bcur,
                                                  W, b, out, N, cap);
}

// Round 19
// 51.749 us; speedup vs baseline: 1.2103x; 1.2103x over previous
//
#include <hip/hip_runtime.h>
#include <hip/hip_fp16.h>

// GCN layer: out = relu( (D^-1/2 A D^-1/2 x) @ W + b )
// N=50000 nodes, E=800000 edges, C=64 channels, fp32 in/out.
//
// R19 = R17 (session-best 56.1us) with bin tuned: 512 threads, BIN_CHUNK=4096
// (doubles per-(block,bucket) write-run length -> better epk coalescing, same
// grid coverage). R18's sort-in-gather fusion regressed (62.6) — reverted.
//
// Build (rebuilt on-device every call; fixed-capacity bucket regions):
//   clearcur: bcur[] = 0 (tiny kernel — never hipMemset tiny buffers, R13)
//   bin:      per-block LDS histogram + per-edge local rank, one reservation
//             atomic per (block,bucket); writes packed (col_lo<<16|src) u32 at
//             bkt*cap + rel
//   build:    512 threads; per-bucket counting sort in LDS -> srcs with
//             8-ALIGNED PADDED per-node segments (pad slots = N -> zero row),
//             seg=(start,deg,dis_bits,0), xsh = half(dis*x); zero row xsh[N]
//   gather:   16-lane group per node, 32 nodes/block: per 8 edges one uint4
//             srcs load + 8 row loads in flight, no tail masks; per-thread
//             64x64 linear from LDS W + ReLU, float4 store.
// No float atomics anywhere (R16: LDS ds_add_f32 accumulation = ~15x cost).

#define C_CH 64
#define BW   128        // bucket width in nodes
#define BSH  7          // log2(BW)
#define MAXBUK 512      // >= ceil(N/BW) = 391
#define BIN_CHUNK 4096  // edges per bin block (196 blocks x 8 waves)
#define NPB  32         // nodes per gather block

// ---- clear bucket cursors ---------------------------------------------------
__global__ void clearcur_kernel(int* __restrict__ bcur, int nbuk) {
    int i = blockIdx.x * blockDim.x + threadIdx.x;
    if (i < nbuk) bcur[i] = 0;
}

// ---- bin: scatter edges into fixed-capacity bucket regions ------------------
__global__ void __launch_bounds__(512)
bin_kernel(const int* __restrict__ row, const int* __restrict__ col,
           int* __restrict__ bcur, unsigned* __restrict__ epk,
           int E, int nbuk, int cap) {
    __shared__ int h[MAXBUK];                 // block-local bucket counts
    __shared__ int rb[MAXBUK];                // block's reserved rel-base per bucket
    __shared__ unsigned short rank[BIN_CHUNK];// per-edge local rank
    int tid = threadIdx.x;
    int e0 = blockIdx.x * BIN_CHUNK;
    int cntE = E - e0; if (cntE > BIN_CHUNK) cntE = BIN_CHUNK;

    for (int i = tid; i < nbuk; i += 512) h[i] = 0;
    __syncthreads();

    const int4* col4 = (const int4*)(col + e0);   // e0 is 4096-aligned
    const int4* row4 = (const int4*)(row + e0);
    int cnt4 = cntE >> 2;
    for (int i = tid; i < cnt4; i += 512) {       // pass 1: ranks (int4 loads)
        int4 c = col4[i];
        rank[4*i+0] = (unsigned short)atomicAdd(&h[c.x >> BSH], 1);
        rank[4*i+1] = (unsigned short)atomicAdd(&h[c.y >> BSH], 1);
        rank[4*i+2] = (unsigned short)atomicAdd(&h[c.z >> BSH], 1);
        rank[4*i+3] = (unsigned short)atomicAdd(&h[c.w >> BSH], 1);
    }
    for (int i = (cnt4 << 2) + tid; i < cntE; i += 512)
        rank[i] = (unsigned short)atomicAdd(&h[col[e0 + i] >> BSH], 1);
    __syncthreads();

    for (int i = tid; i < nbuk; i += 512)         // 1 atomic/(block,bucket)
        rb[i] = h[i] ? atomicAdd(&bcur[i], h[i]) : 0;   // bcur starts at 0
    __syncthreads();

    for (int i = tid; i < cnt4; i += 512) {       // pass 2: write packed edges
        int4 c = col4[i];
        int4 r = row4[i];
        #pragma unroll
        for (int j = 0; j < 4; ++j) {
            int cc = (j == 0) ? c.x : (j == 1) ? c.y : (j == 2) ? c.z : c.w;
            int rr = (j == 0) ? r.x : (j == 1) ? r.y : (j == 2) ? r.z : r.w;
            int bkt = cc >> BSH;
            int rel = rb[bkt] + (int)rank[4*i+j];
            if (rel < cap)                        // safety clamp (never hit here)
                epk[bkt * cap + rel] = ((unsigned)(cc & (BW - 1)) << 16) | (unsigned)rr;
        }
    }
    for (int i = (cnt4 << 2) + tid; i < cntE; i += 512) {
        int cc = col[e0 + i];
        int bkt = cc >> BSH;
        int rel = rb[bkt] + (int)rank[i];
        if (rel < cap)
            epk[bkt * cap + rel] = ((unsigned)(cc & (BW - 1)) << 16) | (unsigned)row[e0 + i];
    }
}

// ---- build: per-bucket counting sort (8-aligned padded segments) ------------
__global__ void __launch_bounds__(512)
build_kernel(const unsigned* __restrict__ epk, const int* __restrict__ bcur,
             const float* __restrict__ x,
             int4* __restrict__ seg,              // (start, deg, dis_bits, 0)
             unsigned short* __restrict__ srcs, __half* __restrict__ xsh,
             int N, int cap) {
    __shared__ int cnt[BW];
    __shared__ int sc[BW];
    __shared__ int cur[BW];
    __shared__ float dv[BW];
    __shared__ int tot;
    __shared__ unsigned short sl[4096];           // cap <= 4096 always
    int tid = threadIdx.x;
    int b   = blockIdx.x;
    int base = b * cap;
    int cb = bcur[b]; if (cb > cap) cb = cap;     // bucket edge count
    int nb0 = b << BSH;
    int nn  = N - nb0; if (nn > BW) nn = BW;

    if (tid < BW) cnt[tid] = 0;
    for (int i = tid; i < cap; i += 512)          // prefill: pad slots -> zero row
        sl[i] = (unsigned short)N;
    __syncthreads();
    for (int i = tid; i < cb; i += 512)
        atomicAdd(&cnt[epk[base + i] >> 16], 1);
    __syncthreads();
    if (tid < BW) sc[tid] = (cnt[tid] + 7) & ~7;  // 8-padded degree
    __syncthreads();
    for (int off = 1; off < BW; off <<= 1) {      // inclusive scan of padded deg
        int t = (tid < BW && tid >= off) ? sc[tid - off] : 0;
        __syncthreads();
        if (tid < BW) sc[tid] += t;
        __syncthreads();
    }
    if (tid < BW) {
        int d  = cnt[tid];
        int dp = (d + 7) & ~7;
        int ex = sc[tid] - dp;                    // 8-aligned exclusive offset
        cur[tid] = ex;
        if (tid == BW - 1) tot = sc[tid];
        if (tid < nn) {
            float di = (d > 0) ? rsqrtf((float)d) : 0.0f;
            dv[tid] = di;
            seg[nb0 + tid] = make_int4(base + ex, d, __float_as_int(di), 0);
        }
    }
    __syncthreads();
    for (int i = tid; i < cb; i += 512) {         // scatter inside LDS
        unsigned p = epk[base + i];
        int pos = atomicAdd(&cur[p >> 16], 1);
        if (pos < cap) sl[pos] = (unsigned short)(p & 0xFFFFu);
    }
    __syncthreads();
    int cbp = tot; if (cbp > cap) cbp = cap;      // padded total (incl. N-fill)
    for (int i = tid; i < cbp; i += 512)          // coalesced copy out
        srcs[base + i] = sl[i];

    // xsh[n][c] = half(dis[n] * x[n][c]) for this bucket's nodes
    int tot2 = nn * (C_CH / 2);
    const float2* x2 = (const float2*)x;
    __half2* o2 = (__half2*)xsh;
    for (int i = tid; i < tot2; i += 512) {
        int nl = i >> 5;
        int c2 = i & 31;
        long long gi = (long long)(nb0 + nl) * (C_CH / 2) + c2;
        float2 v = x2[gi];
        float dn = dv[nl];
        o2[gi] = __floats2half2_rn(v.x * dn, v.y * dn);
    }
    // zero row at index N (gather's padding target)
    if (b == 0 && tid < C_CH / 2)
        o2[(long long)N * (C_CH / 2) + tid] = __floats2half2_rn(0.0f, 0.0f);
}

// ---- gather + aggregate + linear + ReLU (R8-proven form) ---------------------
// 16-lane group per node: lane c4 owns channels [4c4..4c4+3]. Per 8 edges:
// ONE uint4 load of 8 srcs (16B-aligned by construction) + 8 row-loads in
// flight; pad slots hold N -> zero row, so no masks anywhere. Linear:
// per-thread (node g, oc-quad c4), full-unroll kq (measured: no spill, R8/R9).
__global__ void __launch_bounds__(512)
gather_kernel(const uint2* __restrict__ xsh8,    // [(N+1)][16] x 8B
              const unsigned short* __restrict__ srcs,
              const int4* __restrict__ seg,      // (start, deg, dis_bits, 0)
              const float* __restrict__ W, const float* __restrict__ b,
              float* __restrict__ out, int N) {
    __shared__ float Ws[C_CH * C_CH];            // 16 KB
    __shared__ float bs[C_CH];
    __shared__ float ags[NPB][68];               // stride 68: conflict-free float4 rows

    int tid = threadIdx.x;
    {   // stage W as float4
        const float4* W4 = (const float4*)W;
        float4* Ws4 = (float4*)Ws;
        for (int i = tid; i < C_CH * C_CH / 4; i += 512) Ws4[i] = W4[i];
        if (tid < C_CH) bs[tid] = b[tid];
    }

    int g  = tid >> 4;        // group = local node 0..31
    int c4 = tid & 15;        // channel quad
    int t = blockIdx.x * NPB + g;

    if (t < N) {
        float4 acc = make_float4(0.f, 0.f, 0.f, 0.f);
        int4 sg = seg[t];                        // one 16B load: start, deg, dis
        int s0 = sg.x;                           // multiple of 8
        int degp = (sg.y + 7) & ~7;              // 8-padded degree
        for (int eb = 0; eb < degp; eb += 8) {
            uint4 sv = *(const uint4*)(srcs + s0 + eb);   // 8 srcs, one 16B load
            int r0 = (int)(sv.x & 0xFFFFu), r1 = (int)(sv.x >> 16);
            int r2 = (int)(sv.y & 0xFFFFu), r3 = (int)(sv.y >> 16);
            int r4 = (int)(sv.z & 0xFFFFu), r5 = (int)(sv.z >> 16);
            int r6 = (int)(sv.w & 0xFFFFu), r7 = (int)(sv.w >> 16);
            uint2 u0 = xsh8[r0 * 16 + c4];       // 8 independent loads in flight
            uint2 u1 = xsh8[r1 * 16 + c4];
            uint2 u2 = xsh8[r2 * 16 + c4];
            uint2 u3 = xsh8[r3 * 16 + c4];
            uint2 u4 = xsh8[r4 * 16 + c4];
            uint2 u5 = xsh8[r5 * 16 + c4];
            uint2 u6 = xsh8[r6 * 16 + c4];
            uint2 u7 = xsh8[r7 * 16 + c4];
            #pragma unroll
            for (int k = 0; k < 8; ++k) {
                uint2 u = (k==0)?u0:(k==1)?u1:(k==2)?u2:(k==3)?u3:
                          (k==4)?u4:(k==5)?u5:(k==6)?u6:u7;
                float2 f0 = __half22float2(*(__half2*)&u.x);
                float2 f1 = __half22float2(*(__half2*)&u.y);
                acc.x += f0.x; acc.y += f0.y; acc.z += f1.x; acc.w += f1.y;
            }
        }
        float dt = __int_as_float(sg.z);
        acc.x *= dt; acc.y *= dt; acc.z *= dt; acc.w *= dt;
        *(float4*)&ags[g][4 * c4] = acc;
    }
    __syncthreads();

    // linear: same thread mapping (node g, oc-quad c4), k blocked by 4
    if (t < N) {
        float4 o = *(const float4*)&bs[4 * c4];
        #pragma unroll
        for (int kq = 0; kq < C_CH / 4; ++kq) {
            float4 a4 = *(const float4*)&ags[g][4 * kq];
            float4 w0 = *(const float4*)&Ws[(4 * kq + 0) * C_CH + 4 * c4];
            float4 w1 = *(const float4*)&Ws[(4 * kq + 1) * C_CH + 4 * c4];
            float4 w2 = *(const float4*)&Ws[(4 * kq + 2) * C_CH + 4 * c4];
            float4 w3 = *(const float4*)&Ws[(4 * kq + 3) * C_CH + 4 * c4];
            o.x = fmaf(a4.x, w0.x, o.x); o.y = fmaf(a4.x, w0.y, o.y);
            o.z = fmaf(a4.x, w0.z, o.z); o.w = fmaf(a4.x, w0.w, o.w);
            o.x = fmaf(a4.y, w1.x, o.x); o.y = fmaf(a4.y, w1.y, o.y);
            o.z = fmaf(a4.y, w1.z, o.z); o.w = fmaf(a4.y, w1.w, o.w);
            o.x = fmaf(a4.z, w2.x, o.x); o.y = fmaf(a4.z, w2.y, o.y);
            o.z = fmaf(a4.z, w2.z, o.z); o.w = fmaf(a4.z, w2.w, o.w);
            o.x = fmaf(a4.w, w3.x, o.x); o.y = fmaf(a4.w, w3.y, o.y);
            o.z = fmaf(a4.w, w3.z, o.z); o.w = fmaf(a4.w, w3.w, o.w);
        }
        o.x = fmaxf(o.x, 0.f); o.y = fmaxf(o.y, 0.f);
        o.z = fmaxf(o.z, 0.f); o.w = fmaxf(o.w, 0.f);
        *(float4*)&out[(long long)t * C_CH + 4 * c4] = o;   // 256B/group, coalesced
    }
}

extern "C" void kernel_launch(void* const* d_in, const int* in_sizes, int n_in,
                              void* d_out, int out_size, void* d_ws, size_t ws_size,
                              hipStream_t stream) {
    const float* x  = (const float*)d_in[0];
    const int*   ei = (const int*)  d_in[1];
    const float* W  = (const float*)d_in[2];
    const float* b  = (const float*)d_in[3];
    float* out = (float*)d_out;

    const int N = in_sizes[0] / C_CH;
    const int E = in_sizes[1] / 2;
    const int* row = ei;        // edge_index[0]
    const int* col = ei + E;    // edge_index[1]
    const int nbuk = (N + BW - 1) >> BSH;   // 391 (<= MAXBUK)

    // Bucket capacity: mean bucket = E*BW/N ~ 2048, 8-padded +<=448 worst;
    // 4096 gives >40 sigma headroom. Fallback 3072.
    auto need = [&](int cap) {
        return (size_t)nbuk * cap * 6          // epk (4B) + srcs (2B)
             + (size_t)N * 16 + 256            // seg int4
             + (((size_t)nbuk * 4 + 127) & ~(size_t)127)  // bcur (padded)
             + (size_t)(N + 1) * C_CH * 2;     // xsh incl. zero row
    };
    int cap = 4096;
    if (ws_size < need(4096)) cap = 3072;

    char* ws = (char*)d_ws;
    unsigned* epk = (unsigned*)ws;      ws += (size_t)nbuk * cap * 4;
    unsigned short* srcs = (unsigned short*)ws;  ws += (size_t)nbuk * cap * 2;
    int4* seg = (int4*)ws;              ws += (size_t)N * 16;
    int* bcur = (int*)ws;               ws += ((size_t)nbuk * 4 + 127) & ~(size_t)127;
    __half* xsh = (__half*)ws;          // 8B-aligned for uint2 loads

    clearcur_kernel<<<(nbuk + 255) / 256, 256, 0, stream>>>(bcur, nbuk);
    bin_kernel <<<(E + BIN_CHUNK - 1) / BIN_CHUNK, 512, 0, stream>>>(row, col, bcur, epk, E, nbuk, cap);
    build_kernel<<<nbuk, 512, 0, stream>>>(epk, bcur, x, seg, srcs, xsh, N, cap);
    gather_kernel<<<(N + NPB - 1) / NPB, 512, 0, stream>>>((const uint2*)xsh, srcs, seg,
                                                           W, b, out, N);
}